// Round 1
// baseline (717.072 us; speedup 1.0000x reference)
//
#include <hip/hip_runtime.h>
#include <hip/hip_bf16.h>

typedef __hip_bfloat16 bf16t;
using f32x4 = __attribute__((ext_vector_type(4))) float;
using s16x8 = __attribute__((ext_vector_type(8))) short;

#define NTOK 4096
#define DIM 1024
#define HID 2048
#define NEXP 8
#define NMODE 4
#define NGRP 13
#define SLOTS_PAD 16512   // 16384 + 128 pad for partial-tile reads

// ---------------- workspace layout (bytes) ----------------
static constexpr size_t SZ_WT    = (size_t)NGRP * HID * DIM * 2;   // bf16, 54,525,952
static constexpr size_t OFF_WT1  = 0;
static constexpr size_t OFF_WT2  = OFF_WT1 + SZ_WT;
static constexpr size_t OFF_HBUF = OFF_WT2 + SZ_WT;
static constexpr size_t SZ_HBUF  = (size_t)SLOTS_PAD * HID * 2;
static constexpr size_t OFF_B1   = OFF_HBUF + SZ_HBUF;
static constexpr size_t OFF_B2   = OFF_B1 + (size_t)NGRP * HID * 4;
static constexpr size_t OFF_TP   = OFF_B2 + (size_t)NGRP * DIM * 4;
static constexpr size_t OFF_TI   = OFF_TP + (size_t)NTOK * 2 * 4;
static constexpr size_t OFF_LIST = OFF_TI + (size_t)NTOK * 2 * 4;
static constexpr size_t OFF_CNT  = OFF_LIST + (size_t)SLOTS_PAD * 4;
static constexpr size_t OFF_CUR  = OFF_CNT + 64;
static constexpr size_t OFF_GRP  = OFF_CUR + 64;
static constexpr size_t WS_NEED  = OFF_GRP + 256;

static __device__ __forceinline__ short fb(float f) {
    bf16t h = __float2bfloat16(f);
    short s; __builtin_memcpy(&s, &h, 2); return s;
}
static __device__ __forceinline__ float gelu_tanh(float x) {
    float u = 0.7978845608028654f * (x + 0.044715f * x * x * x);
    return 0.5f * x * (1.0f + tanhf(u));
}

// ---------------- router: logits, softmax, top-2, counts ----------------
__global__ void router_k(const float* __restrict__ hidden, const int* __restrict__ mode_ids,
                         const float* __restrict__ rw, const float* __restrict__ rb,
                         float* __restrict__ aux_logits, float* __restrict__ aux_idx,
                         float* __restrict__ aux_probs,
                         float* __restrict__ topk_p, int* __restrict__ topk_i,
                         int* __restrict__ cnts) {
    const int t = blockIdx.x;
    const int lane = threadIdx.x;
    const float* x = hidden + (size_t)t * DIM;
    float acc[NEXP];
#pragma unroll
    for (int e = 0; e < NEXP; e++) acc[e] = 0.f;
#pragma unroll
    for (int i = 0; i < DIM / 64; i++) {
        int d = i * 64 + lane;
        float xv = x[d];
        const float4* w = (const float4*)(rw + (size_t)d * NEXP);
        float4 w0 = w[0], w1 = w[1];
        acc[0] += xv * w0.x; acc[1] += xv * w0.y; acc[2] += xv * w0.z; acc[3] += xv * w0.w;
        acc[4] += xv * w1.x; acc[5] += xv * w1.y; acc[6] += xv * w1.z; acc[7] += xv * w1.w;
    }
#pragma unroll
    for (int off = 32; off >= 1; off >>= 1) {
#pragma unroll
        for (int e = 0; e < NEXP; e++) acc[e] += __shfl_down(acc[e], off, 64);
    }
    if (lane == 0) {
        float lg[NEXP], pb[NEXP];
        float mx = -1e30f;
#pragma unroll
        for (int e = 0; e < NEXP; e++) { lg[e] = acc[e] + rb[e]; mx = fmaxf(mx, lg[e]); }
        float s = 0.f;
#pragma unroll
        for (int e = 0; e < NEXP; e++) { pb[e] = expf(lg[e] - mx); s += pb[e]; }
        float inv = 1.f / s;
#pragma unroll
        for (int e = 0; e < NEXP; e++) { pb[e] *= inv; aux_logits[(size_t)t * NEXP + e] = lg[e]; }
        // top-2 with jax.lax.top_k tie semantics (lower index wins on tie)
        int i1 = 0;
        for (int e = 1; e < NEXP; e++) if (pb[e] > pb[i1]) i1 = e;
        int i2 = (i1 == 0) ? 1 : 0;
        for (int e = 0; e < NEXP; e++) { if (e == i1) continue; if (pb[e] > pb[i2]) i2 = e; }
        aux_idx[t * 2] = (float)i1;  aux_idx[t * 2 + 1] = (float)i2;
        aux_probs[t * 2] = pb[i1];   aux_probs[t * 2 + 1] = pb[i2];
        topk_p[t * 2] = pb[i1];      topk_p[t * 2 + 1] = pb[i2];
        topk_i[t * 2] = i1;          topk_i[t * 2 + 1] = i2;
        atomicAdd(&cnts[mode_ids[t]], 1);
        atomicAdd(&cnts[NMODE + i1], 1);
        atomicAdd(&cnts[NMODE + i2], 1);
    }
}

// ---------------- transpose + f32->bf16 convert of all 26 weight matrices ----------------
struct TPtr {
    const float* s_w1; const float* s_w2;
    const float* m_w1; const float* m_w2;
    const float* r_w1; const float* r_w2;
};
__global__ void transpose_convert_k(TPtr tp, bf16t* __restrict__ wt1, bf16t* __restrict__ wt2) {
    const size_t MSZ = (size_t)DIM * HID;
    int z = blockIdx.z;
    const float* src; bf16t* dst; int R, C;
    if (z == 0)      { src = tp.s_w1;                    dst = wt1;                 R = DIM; C = HID; }
    else if (z == 1) { src = tp.s_w2;                    dst = wt2;                 R = HID; C = DIM; }
    else if (z < 6)  { int m = z - 2;  src = tp.m_w1 + (size_t)m * MSZ; dst = wt1 + (size_t)(1 + m) * MSZ; R = DIM; C = HID; }
    else if (z < 10) { int m = z - 6;  src = tp.m_w2 + (size_t)m * MSZ; dst = wt2 + (size_t)(1 + m) * MSZ; R = HID; C = DIM; }
    else if (z < 18) { int e = z - 10; src = tp.r_w1 + (size_t)e * MSZ; dst = wt1 + (size_t)(5 + e) * MSZ; R = DIM; C = HID; }
    else             { int e = z - 18; src = tp.r_w2 + (size_t)e * MSZ; dst = wt2 + (size_t)(5 + e) * MSZ; R = HID; C = DIM; }
    int c0 = blockIdx.x * 64, r0 = blockIdx.y * 64;
    if (c0 >= C || r0 >= R) return;
    __shared__ float lds[64][65];
    const int t = threadIdx.x;
#pragma unroll
    for (int i = 0; i < 16; i++) {
        int r = i * 4 + (t >> 6), c = t & 63;
        lds[r][c] = src[(size_t)(r0 + r) * C + (c0 + c)];
    }
    __syncthreads();
#pragma unroll
    for (int j = 0; j < 8; j++) {
        int c = j * 8 + (t >> 5);
        int rp = (t & 31) * 2;
        unsigned lo = (unsigned short)fb(lds[rp][c]);
        unsigned hi = (unsigned short)fb(lds[rp + 1][c]);
        *(unsigned*)((char*)dst + ((size_t)(c0 + c) * R + (r0 + rp)) * 2) = (hi << 16) | lo;
    }
}

// ---------------- concat biases per group ----------------
__global__ void biascat_k(const float* __restrict__ sb1, const float* __restrict__ mb1, const float* __restrict__ rb1,
                          const float* __restrict__ sb2, const float* __restrict__ mb2, const float* __restrict__ rb2,
                          float* __restrict__ B1c, float* __restrict__ B2c) {
    int i = blockIdx.x * 256 + threadIdx.x;
    if (i < NGRP * HID) {
        int g = i / HID, h = i % HID;
        B1c[i] = (g == 0) ? sb1[h] : (g < 5) ? mb1[(g - 1) * HID + h] : rb1[(g - 5) * HID + h];
    }
    if (i < NGRP * DIM) {
        int g = i / DIM, d = i % DIM;
        B2c[i] = (g == 0) ? sb2[d] : (g < 5) ? mb2[(g - 1) * DIM + d] : rb2[(g - 5) * DIM + d];
    }
}

// ---------------- scan: group descriptors + cursors ----------------
__global__ void scan_k(const int* __restrict__ cnts, int* __restrict__ cursors, int4* __restrict__ groups) {
    if (threadIdx.x != 0 || blockIdx.x != 0) return;
    groups[0] = make_int4(0, NTOK, 0, 0);
    int off = NTOK;
    for (int m = 0; m < NMODE; m++) {
        groups[1 + m] = make_int4(off, cnts[m], 1 + m, 0);
        cursors[m] = off;
        off += cnts[m];
    }
    off = 2 * NTOK;
    for (int e = 0; e < NEXP; e++) {
        groups[5 + e] = make_int4(off, cnts[NMODE + e], 5 + e, 0);
        cursors[NMODE + e] = off;
        off += cnts[NMODE + e];
    }
}

// ---------------- fill slot lists ----------------
__global__ void fill_k(const int* __restrict__ mode_ids, const int* __restrict__ topk_i,
                       int* __restrict__ cursors, int* __restrict__ list) {
    int t = blockIdx.x * 256 + threadIdx.x;
    if (t >= NTOK) return;
    list[t] = t << 1;                                 // shared: identity
    int m = mode_ids[t];
    int pos = atomicAdd(&cursors[m], 1);
    list[pos] = t << 1;
    int e0 = topk_i[t * 2], e1 = topk_i[t * 2 + 1];
    pos = atomicAdd(&cursors[NMODE + e0], 1); list[pos] = (t << 1);
    pos = atomicAdd(&cursors[NMODE + e1], 1); list[pos] = (t << 1) | 1;
}

// ---------------- grouped FFN GEMM ----------------
// STAGE 1: h = gelu(X @ W1 + b1)  -> Hbuf (bf16)   [K=1024, N=2048], A from f32 hidden via list gather
// STAGE 2: o = h @ W2 + b2        -> atomicAdd out [K=2048, N=1024], scaled by routed prob
template <int STAGE>
__global__ __launch_bounds__(256) void ffn_gemm_k(
    const float* __restrict__ hidden,
    const bf16t* __restrict__ hbuf_in,
    const bf16t* __restrict__ wt,
    const float* __restrict__ bias,
    bf16t* __restrict__ hbuf_out,
    float* __restrict__ out,
    const float* __restrict__ topk_p,
    const int* __restrict__ list,
    const int4* __restrict__ groups) {
    constexpr int K = (STAGE == 1) ? DIM : HID;
    constexpr int N = (STAGE == 1) ? HID : DIM;
    constexpr int NK = K / 64;

    const int4 g = groups[blockIdx.z];
    const int slot_base = g.x, rows = g.y, gidx = g.z;
    const int row0 = blockIdx.y * 128;
    if (row0 >= rows) return;
    const int n0 = blockIdx.x * 128;

    __shared__ alignas(16) char As[128 * 64 * 2];
    __shared__ alignas(16) char Bs[128 * 64 * 2];

    const int tid = threadIdx.x;
    const int lane = tid & 63;
    const int wave = tid >> 6;
    const int wm = wave >> 1, wn = wave & 1;

    // staging geometry: pass p covers rows srow+32p, 16B chunk schunk
    const int srow = tid >> 3;    // 0..31
    const int schunk = tid & 7;   // 0..7
    int aofs[4];
#pragma unroll
    for (int p = 0; p < 4; p++) {
        int r = srow + 32 * p;
        int slot = slot_base + row0 + r;
        if (STAGE == 1) aofs[p] = (list[slot] >> 1) * DIM;
        else            aofs[p] = slot * HID;
    }
    const bf16t* wbase = wt + (size_t)gidx * ((size_t)K * N);
    int bofs[4];
#pragma unroll
    for (int p = 0; p < 4; p++) bofs[p] = (n0 + srow + 32 * p) * K;

    f32x4 acc[4][4];
    const f32x4 zero = {0.f, 0.f, 0.f, 0.f};
#pragma unroll
    for (int i = 0; i < 4; i++)
#pragma unroll
        for (int j = 0; j < 4; j++) acc[i][j] = zero;

    for (int kt = 0; kt < NK; ++kt) {
        const int kbase = kt * 64;
#pragma unroll
        for (int p = 0; p < 4; p++) {
            const int r = srow + 32 * p;
            const int b = (r * 128 + schunk * 16) ^ ((r & 7) << 4);
            if (STAGE == 1) {
                const float* src = hidden + aofs[p] + kbase + schunk * 8;
                const float4 f0 = *(const float4*)src;
                const float4 f1 = *(const float4*)(src + 4);
                s16x8 v;
                v[0] = fb(f0.x); v[1] = fb(f0.y); v[2] = fb(f0.z); v[3] = fb(f0.w);
                v[4] = fb(f1.x); v[5] = fb(f1.y); v[6] = fb(f1.z); v[7] = fb(f1.w);
                *(s16x8*)(As + b) = v;
            } else {
                *(s16x8*)(As + b) = *(const s16x8*)(hbuf_in + aofs[p] + kbase + schunk * 8);
            }
            *(s16x8*)(Bs + b) = *(const s16x8*)(wbase + bofs[p] + kbase + schunk * 8);
        }
        __syncthreads();
#pragma unroll
        for (int kk = 0; kk < 2; kk++) {
            const int kbyte = kk * 64 + ((lane >> 4) << 4);
            s16x8 av[4], bv[4];
#pragma unroll
            for (int i = 0; i < 4; i++) {
                const int ra = wm * 64 + i * 16 + (lane & 15);
                av[i] = *(const s16x8*)(As + ((ra * 128 + kbyte) ^ ((ra & 7) << 4)));
                const int rb2 = wn * 64 + i * 16 + (lane & 15);
                bv[i] = *(const s16x8*)(Bs + ((rb2 * 128 + kbyte) ^ ((rb2 & 7) << 4)));
            }
#pragma unroll
            for (int mi = 0; mi < 4; mi++)
#pragma unroll
                for (int ni = 0; ni < 4; ni++)
                    acc[mi][ni] = __builtin_amdgcn_mfma_f32_16x16x32_bf16(av[mi], bv[ni], acc[mi][ni], 0, 0, 0);
        }
        __syncthreads();
    }

    const int lr = lane >> 4, lc = lane & 15;
    if (STAGE == 1) {
#pragma unroll
        for (int ni = 0; ni < 4; ni++) {
            const int col = n0 + wn * 64 + ni * 16 + lc;
            const float bvv = bias[gidx * HID + col];
#pragma unroll
            for (int mi = 0; mi < 4; mi++) {
#pragma unroll
                for (int r = 0; r < 4; r++) {
                    const int row = wm * 64 + mi * 16 + lr * 4 + r;
                    if (row0 + row < rows) {
                        float v = gelu_tanh(acc[mi][ni][r] + bvv);
                        hbuf_out[(size_t)(slot_base + row0 + row) * HID + col] = __float2bfloat16(v);
                    }
                }
            }
        }
    } else {
#pragma unroll
        for (int mi = 0; mi < 4; mi++) {
#pragma unroll
            for (int r = 0; r < 4; r++) {
                const int row = wm * 64 + mi * 16 + lr * 4 + r;
                if (row0 + row >= rows) continue;
                const int slot = slot_base + row0 + row;
                const int packed = list[slot];
                const int tok = packed >> 1;
                float p = 1.0f;
                if (gidx >= 5) p = topk_p[tok * 2 + (packed & 1)];
                float* orow = out + (size_t)tok * DIM;
#pragma unroll
                for (int ni = 0; ni < 4; ni++) {
                    const int col = n0 + wn * 64 + ni * 16 + lc;
                    const float v = acc[mi][ni][r] + bias[gidx * DIM + col];
                    atomicAdd(orow + col, p * v);
                }
            }
        }
    }
}

extern "C" void kernel_launch(void* const* d_in, const int* in_sizes, int n_in,
                              void* d_out, int out_size, void* d_ws, size_t ws_size,
                              hipStream_t stream) {
    (void)in_sizes; (void)n_in;
    if (ws_size < WS_NEED) return;  // workspace too small; bail cleanly

    const float* hidden   = (const float*)d_in[0];
    const int*   mode_ids = (const int*)d_in[1];
    const float* router_w = (const float*)d_in[2];
    const float* router_b = (const float*)d_in[3];
    TPtr tp;
    tp.s_w1 = (const float*)d_in[4];
    const float* s_b1 = (const float*)d_in[5];
    tp.s_w2 = (const float*)d_in[6];
    const float* s_b2 = (const float*)d_in[7];
    tp.m_w1 = (const float*)d_in[8];
    const float* m_b1 = (const float*)d_in[9];
    tp.m_w2 = (const float*)d_in[10];
    const float* m_b2 = (const float*)d_in[11];
    tp.r_w1 = (const float*)d_in[12];
    const float* r_b1 = (const float*)d_in[13];
    tp.r_w2 = (const float*)d_in[14];
    const float* r_b2 = (const float*)d_in[15];

    char* ws = (char*)d_ws;
    bf16t* WT1   = (bf16t*)(ws + OFF_WT1);
    bf16t* WT2   = (bf16t*)(ws + OFF_WT2);
    bf16t* Hbuf  = (bf16t*)(ws + OFF_HBUF);
    float* B1c   = (float*)(ws + OFF_B1);
    float* B2c   = (float*)(ws + OFF_B2);
    float* topkp = (float*)(ws + OFF_TP);
    int*   topki = (int*)(ws + OFF_TI);
    int*   list  = (int*)(ws + OFF_LIST);
    int*   cnts  = (int*)(ws + OFF_CNT);
    int*   curs  = (int*)(ws + OFF_CUR);
    int4*  grps  = (int4*)(ws + OFF_GRP);

    float* out        = (float*)d_out;
    float* aux_logits = out + (size_t)NTOK * DIM;
    float* aux_idx    = aux_logits + (size_t)NTOK * NEXP;
    float* aux_probs  = aux_idx + (size_t)NTOK * 2;

    hipMemsetAsync(d_out, 0, (size_t)out_size * 4, stream);
    hipMemsetAsync(ws + OFF_LIST, 0, OFF_GRP - OFF_LIST, stream);

    transpose_convert_k<<<dim3(32, 32, 26), 256, 0, stream>>>(tp, WT1, WT2);
    biascat_k<<<(NGRP * HID + 255) / 256, 256, 0, stream>>>(s_b1, m_b1, r_b1, s_b2, m_b2, r_b2, B1c, B2c);
    router_k<<<NTOK, 64, 0, stream>>>(hidden, mode_ids, router_w, router_b,
                                      aux_logits, aux_idx, aux_probs, topkp, topki, cnts);
    scan_k<<<1, 64, 0, stream>>>(cnts, curs, grps);
    fill_k<<<(NTOK + 255) / 256, 256, 0, stream>>>(mode_ids, topki, curs, list);
    ffn_gemm_k<1><<<dim3(HID / 128, 32, NGRP), 256, 0, stream>>>(
        hidden, Hbuf, WT1, B1c, Hbuf, out, topkp, list, grps);
    ffn_gemm_k<2><<<dim3(DIM / 128, 32, NGRP), 256, 0, stream>>>(
        hidden, Hbuf, WT2, B2c, Hbuf, out, topkp, list, grps);
}

// Round 2
// 613.463 us; speedup vs baseline: 1.1689x; 1.1689x over previous
//
#include <hip/hip_runtime.h>
#include <hip/hip_bf16.h>

typedef __hip_bfloat16 bf16t;
using f32x4 = __attribute__((ext_vector_type(4))) float;
using s16x8 = __attribute__((ext_vector_type(8))) short;

#define NTOK 4096
#define DIM 1024
#define HID 2048
#define NEXP 8
#define NMODE 4
#define NGRP 13
#define SLOTS_PAD 16512   // 16384 + 128 pad for partial-tile reads
#define MAXT 144          // max row-tiles over all groups (<=138 by construction)

// ---------------- workspace layout (bytes) ----------------
static constexpr size_t SZ_WT    = (size_t)NGRP * HID * DIM * 2;   // 54,525,952
static constexpr size_t OFF_WT1  = 0;
static constexpr size_t OFF_OBUF = 0;                               // overlay: WT1 dead before GEMM2
static constexpr size_t OFF_WT2  = OFF_WT1 + SZ_WT;
static constexpr size_t OFF_HBUF = OFF_WT2 + SZ_WT;
static constexpr size_t SZ_HBUF  = (size_t)SLOTS_PAD * HID * 2;
static constexpr size_t OFF_XBF  = OFF_HBUF + SZ_HBUF;
static constexpr size_t SZ_XBF   = (size_t)NTOK * DIM * 2;
static constexpr size_t OFF_B1   = OFF_XBF + SZ_XBF;
static constexpr size_t OFF_B2   = OFF_B1 + (size_t)NGRP * HID * 4;
static constexpr size_t OFF_TP   = OFF_B2 + (size_t)NGRP * DIM * 4;
static constexpr size_t OFF_TI   = OFF_TP + (size_t)NTOK * 2 * 4;
static constexpr size_t OFF_MS   = OFF_TI + (size_t)NTOK * 2 * 4;
static constexpr size_t OFF_R0S  = OFF_MS + (size_t)NTOK * 4;
static constexpr size_t OFF_R1S  = OFF_R0S + (size_t)NTOK * 4;
static constexpr size_t OFF_LIST = OFF_R1S + (size_t)NTOK * 4;
static constexpr size_t OFF_CNT  = OFF_LIST + (size_t)SLOTS_PAD * 4;
static constexpr size_t OFF_CUR  = OFF_CNT + 64;
static constexpr size_t OFF_TC   = OFF_CUR + 64;
static constexpr size_t OFF_TD   = OFF_TC + 16;
static constexpr size_t WS_NEED  = OFF_TD + (size_t)MAXT * 16;

static __device__ __forceinline__ short fb(float f) {
    bf16t h = __float2bfloat16(f);
    short s; __builtin_memcpy(&s, &h, 2); return s;
}
static __device__ __forceinline__ float bf2f(short s) {
    unsigned u = ((unsigned)(unsigned short)s) << 16;
    float f; __builtin_memcpy(&f, &u, 4); return f;
}
static __device__ __forceinline__ float gelu_tanh(float x) {
    float u = 0.7978845608028654f * (x + 0.044715f * x * x * x);
    return 0.5f * x * (1.0f + tanhf(u));
}

typedef __attribute__((address_space(3))) void lds_void;
typedef const __attribute__((address_space(1))) void gbl_void;
static __device__ __forceinline__ void gload16(const void* g, void* l) {
    __builtin_amdgcn_global_load_lds((gbl_void*)g, (lds_void*)l, 16, 0, 0);
}

// ---------------- hidden f32 -> bf16 ----------------
__global__ void xconv_k(const float* __restrict__ h, bf16t* __restrict__ xbf) {
    const size_t i = ((size_t)blockIdx.x * 256 + threadIdx.x) * 8;
    const float4 a = *(const float4*)(h + i);
    const float4 b = *(const float4*)(h + i + 4);
    s16x8 v;
    v[0] = fb(a.x); v[1] = fb(a.y); v[2] = fb(a.z); v[3] = fb(a.w);
    v[4] = fb(b.x); v[5] = fb(b.y); v[6] = fb(b.z); v[7] = fb(b.w);
    *(s16x8*)(xbf + i) = v;
}

// ---------------- router ----------------
__global__ void router_k(const float* __restrict__ hidden, const int* __restrict__ mode_ids,
                         const float* __restrict__ rw, const float* __restrict__ rb,
                         float* __restrict__ aux_logits, float* __restrict__ aux_idx,
                         float* __restrict__ aux_probs,
                         float* __restrict__ topk_p, int* __restrict__ topk_i,
                         int* __restrict__ cnts) {
    const int t = blockIdx.x;
    const int lane = threadIdx.x;
    const float* x = hidden + (size_t)t * DIM;
    float acc[NEXP];
#pragma unroll
    for (int e = 0; e < NEXP; e++) acc[e] = 0.f;
#pragma unroll
    for (int i = 0; i < DIM / 64; i++) {
        int d = i * 64 + lane;
        float xv = x[d];
        const float4* w = (const float4*)(rw + (size_t)d * NEXP);
        float4 w0 = w[0], w1 = w[1];
        acc[0] += xv * w0.x; acc[1] += xv * w0.y; acc[2] += xv * w0.z; acc[3] += xv * w0.w;
        acc[4] += xv * w1.x; acc[5] += xv * w1.y; acc[6] += xv * w1.z; acc[7] += xv * w1.w;
    }
#pragma unroll
    for (int off = 32; off >= 1; off >>= 1) {
#pragma unroll
        for (int e = 0; e < NEXP; e++) acc[e] += __shfl_down(acc[e], off, 64);
    }
    if (lane == 0) {
        float lg[NEXP], pb[NEXP];
        float mx = -1e30f;
#pragma unroll
        for (int e = 0; e < NEXP; e++) { lg[e] = acc[e] + rb[e]; mx = fmaxf(mx, lg[e]); }
        float s = 0.f;
#pragma unroll
        for (int e = 0; e < NEXP; e++) { pb[e] = expf(lg[e] - mx); s += pb[e]; }
        float inv = 1.f / s;
#pragma unroll
        for (int e = 0; e < NEXP; e++) { pb[e] *= inv; aux_logits[(size_t)t * NEXP + e] = lg[e]; }
        int i1 = 0;
        for (int e = 1; e < NEXP; e++) if (pb[e] > pb[i1]) i1 = e;
        int i2 = (i1 == 0) ? 1 : 0;
        for (int e = 0; e < NEXP; e++) { if (e == i1) continue; if (pb[e] > pb[i2]) i2 = e; }
        aux_idx[t * 2] = (float)i1;  aux_idx[t * 2 + 1] = (float)i2;
        aux_probs[t * 2] = pb[i1];   aux_probs[t * 2 + 1] = pb[i2];
        topk_p[t * 2] = pb[i1];      topk_p[t * 2 + 1] = pb[i2];
        topk_i[t * 2] = i1;          topk_i[t * 2 + 1] = i2;
        atomicAdd(&cnts[mode_ids[t]], 1);
        atomicAdd(&cnts[NMODE + i1], 1);
        atomicAdd(&cnts[NMODE + i2], 1);
    }
}

// ---------------- transpose + f32->bf16 of all 26 weight matrices ----------------
struct TPtr {
    const float* s_w1; const float* s_w2;
    const float* m_w1; const float* m_w2;
    const float* r_w1; const float* r_w2;
};
__global__ void transpose_convert_k(TPtr tp, bf16t* __restrict__ wt1, bf16t* __restrict__ wt2) {
    const size_t MSZ = (size_t)DIM * HID;
    int z = blockIdx.z;
    const float* src; bf16t* dst; int R, C;
    if (z == 0)      { src = tp.s_w1;                    dst = wt1;                 R = DIM; C = HID; }
    else if (z == 1) { src = tp.s_w2;                    dst = wt2;                 R = HID; C = DIM; }
    else if (z < 6)  { int m = z - 2;  src = tp.m_w1 + (size_t)m * MSZ; dst = wt1 + (size_t)(1 + m) * MSZ; R = DIM; C = HID; }
    else if (z < 10) { int m = z - 6;  src = tp.m_w2 + (size_t)m * MSZ; dst = wt2 + (size_t)(1 + m) * MSZ; R = HID; C = DIM; }
    else if (z < 18) { int e = z - 10; src = tp.r_w1 + (size_t)e * MSZ; dst = wt1 + (size_t)(5 + e) * MSZ; R = DIM; C = HID; }
    else             { int e = z - 18; src = tp.r_w2 + (size_t)e * MSZ; dst = wt2 + (size_t)(5 + e) * MSZ; R = HID; C = DIM; }
    int c0 = blockIdx.x * 64, r0 = blockIdx.y * 64;
    if (c0 >= C || r0 >= R) return;
    __shared__ float lds[64][65];
    const int t = threadIdx.x;
#pragma unroll
    for (int i = 0; i < 16; i++) {
        int r = i * 4 + (t >> 6), c = t & 63;
        lds[r][c] = src[(size_t)(r0 + r) * C + (c0 + c)];
    }
    __syncthreads();
#pragma unroll
    for (int j = 0; j < 8; j++) {
        int c = j * 8 + (t >> 5);
        int rp = (t & 31) * 2;
        unsigned lo = (unsigned short)fb(lds[rp][c]);
        unsigned hi = (unsigned short)fb(lds[rp + 1][c]);
        *(unsigned*)((char*)dst + ((size_t)(c0 + c) * R + (r0 + rp)) * 2) = (hi << 16) | lo;
    }
}

// ---------------- concat biases ----------------
__global__ void biascat_k(const float* __restrict__ sb1, const float* __restrict__ mb1, const float* __restrict__ rb1,
                          const float* __restrict__ sb2, const float* __restrict__ mb2, const float* __restrict__ rb2,
                          float* __restrict__ B1c, float* __restrict__ B2c) {
    int i = blockIdx.x * 256 + threadIdx.x;
    if (i < NGRP * HID) {
        int g = i / HID, h = i % HID;
        B1c[i] = (g == 0) ? sb1[h] : (g < 5) ? mb1[(g - 1) * HID + h] : rb1[(g - 5) * HID + h];
    }
    if (i < NGRP * DIM) {
        int g = i / DIM, d = i % DIM;
        B2c[i] = (g == 0) ? sb2[d] : (g < 5) ? mb2[(g - 1) * DIM + d] : rb2[(g - 5) * DIM + d];
    }
}

// ---------------- scan: cursors + tile descriptors ----------------
__global__ void scan_k(const int* __restrict__ cnts, int* __restrict__ cursors,
                       int4* __restrict__ tdesc, int* __restrict__ tcount) {
    if (threadIdx.x != 0 || blockIdx.x != 0) return;
    int nt = 0;
    // group 0: shared (identity, NTOK rows)
    for (int r0 = 0; r0 < NTOK; r0 += 128) tdesc[nt++] = make_int4(r0, 128, 0, 0);
    int off = NTOK;
    for (int m = 0; m < NMODE; m++) {
        int c = cnts[m];
        cursors[m] = off;
        for (int r0 = 0; r0 < c; r0 += 128) tdesc[nt++] = make_int4(off + r0, min(128, c - r0), 1 + m, 0);
        off += c;
    }
    off = 2 * NTOK;
    for (int e = 0; e < NEXP; e++) {
        int c = cnts[NMODE + e];
        cursors[NMODE + e] = off;
        for (int r0 = 0; r0 < c; r0 += 128) tdesc[nt++] = make_int4(off + r0, min(128, c - r0), 5 + e, 0);
        off += c;
    }
    tcount[0] = nt;
}

// ---------------- fill slot lists + inverse maps ----------------
__global__ void fill_k(const int* __restrict__ mode_ids, const int* __restrict__ topk_i,
                       int* __restrict__ cursors, int* __restrict__ list,
                       int* __restrict__ ms, int* __restrict__ r0s, int* __restrict__ r1s) {
    int t = blockIdx.x * 256 + threadIdx.x;
    if (t >= NTOK) return;
    list[t] = t << 1;                                 // shared: identity
    int m = mode_ids[t];
    int pos = atomicAdd(&cursors[m], 1);
    list[pos] = t << 1;  ms[t] = pos;
    int e0 = topk_i[t * 2], e1 = topk_i[t * 2 + 1];
    pos = atomicAdd(&cursors[NMODE + e0], 1); list[pos] = t << 1;       r0s[t] = pos;
    pos = atomicAdd(&cursors[NMODE + e1], 1); list[pos] = (t << 1) | 1; r1s[t] = pos;
}

// ---------------- grouped FFN GEMM (m97 structure: global_load_lds + swizzled LDS) ----------------
// STAGE 1: Hbuf[slot] = gelu(Xbf[tok(slot)] @ W1[g] + b1[g])      K=1024, N=2048
// STAGE 2: Obuf[slot] = Hbuf[slot] @ W2[g] + b2[g]                K=2048, N=1024
template <int STAGE>
__global__ __launch_bounds__(256) void ffn_gemm_k(
    const bf16t* __restrict__ xbf,
    const bf16t* __restrict__ hbuf,
    const bf16t* __restrict__ wt,
    const float* __restrict__ bias,
    bf16t* __restrict__ obuf,
    const int* __restrict__ list,
    const int4* __restrict__ tdesc,
    const int* __restrict__ tcount) {
    constexpr int K = (STAGE == 1) ? DIM : HID;
    constexpr int N = (STAGE == 1) ? HID : DIM;
    constexpr int NK = K / 64;
    constexpr int NTN = N / 128;
    constexpr int NWG = NTN * MAXT;   // divisible by 8

    // bijective XCD swizzle: each XCD walks row-tiles of one n-tile consecutively
    const int lin = blockIdx.x;
    const int wg = (lin & 7) * (NWG >> 3) + (lin >> 3);
    const int ntile = wg / MAXT;
    const int tix = wg - ntile * MAXT;
    if (tix >= tcount[0]) return;
    const int4 td = tdesc[tix];
    const int slot0 = td.x, rows = td.y, gidx = td.z;
    const int n0 = ntile * 128;

    __shared__ alignas(16) char As[128 * 64 * 2];
    __shared__ alignas(16) char Bs[128 * 64 * 2];

    const int tid = threadIdx.x;
    const int lane = tid & 63;
    const int wave = tid >> 6;
    const int wm = wave >> 1, wn = wave & 1;

    // staging: thread covers rows {p*32+srow}, 16B chunk schunk; source chunk
    // inverse-swizzled so linear LDS dest + swizzled read = st-style layout
    const int srow = tid >> 3;    // 0..31
    const int schunk = tid & 7;   // 0..7
    const int csw = (schunk ^ (srow & 7)) << 3;   // element offset in row
    const bf16t* wbase = wt + (size_t)gidx * ((size_t)K * N);
    const bf16t* ap[4];
    const bf16t* bp[4];
#pragma unroll
    for (int p = 0; p < 4; p++) {
        const int r = p * 32 + srow;
        if (STAGE == 1) ap[p] = xbf + (size_t)(list[slot0 + r] >> 1) * DIM + csw;
        else            ap[p] = hbuf + (size_t)(slot0 + r) * HID + csw;
        bp[p] = wbase + (size_t)(n0 + r) * K + csw;
    }
    char* lA = As + srow * 128 + schunk * 16;
    char* lB = Bs + srow * 128 + schunk * 16;

    f32x4 acc[4][4];
    const f32x4 zero = {0.f, 0.f, 0.f, 0.f};
#pragma unroll
    for (int i = 0; i < 4; i++)
#pragma unroll
        for (int j = 0; j < 4; j++) acc[i][j] = zero;

    for (int kt = 0; kt < NK; ++kt) {
#pragma unroll
        for (int p = 0; p < 4; p++) {
            gload16(ap[p], lA + p * 4096);
            gload16(bp[p], lB + p * 4096);
            ap[p] += 64; bp[p] += 64;
        }
        __syncthreads();
#pragma unroll
        for (int kk = 0; kk < 2; kk++) {
            const int kbyte = kk * 64 + ((lane >> 4) << 4);
            s16x8 av[4], bv[4];
#pragma unroll
            for (int i = 0; i < 4; i++) {
                const int ra = wm * 64 + i * 16 + (lane & 15);
                av[i] = *(const s16x8*)(As + ((ra * 128 + kbyte) ^ ((ra & 7) << 4)));
                const int rb = wn * 64 + i * 16 + (lane & 15);
                bv[i] = *(const s16x8*)(Bs + ((rb * 128 + kbyte) ^ ((rb & 7) << 4)));
            }
#pragma unroll
            for (int mi = 0; mi < 4; mi++)
#pragma unroll
                for (int ni = 0; ni < 4; ni++)
                    acc[mi][ni] = __builtin_amdgcn_mfma_f32_16x16x32_bf16(av[mi], bv[ni], acc[mi][ni], 0, 0, 0);
        }
        __syncthreads();
    }

    const int lr = lane >> 4, lc = lane & 15;
#pragma unroll
    for (int ni = 0; ni < 4; ni++) {
        const int col = n0 + wn * 64 + ni * 16 + lc;
        const float bvv = bias[gidx * N + col];
#pragma unroll
        for (int mi = 0; mi < 4; mi++) {
#pragma unroll
            for (int r = 0; r < 4; r++) {
                const int row = wm * 64 + mi * 16 + lr * 4 + r;
                if (row < rows) {
                    float v = acc[mi][ni][r] + bvv;
                    if (STAGE == 1) v = gelu_tanh(v);
                    obuf[(size_t)(slot0 + row) * N + col] = __float2bfloat16(v);
                }
            }
        }
    }
}

// ---------------- final gather-reduce: out[t] = sh + mode + p0*r0 + p1*r1 ----------------
__global__ void reduce_k(const bf16t* __restrict__ ob,
                         const int* __restrict__ ms, const int* __restrict__ r0s, const int* __restrict__ r1s,
                         const float* __restrict__ topkp, float* __restrict__ out) {
    const int t = blockIdx.x;
    const int d = threadIdx.x * 8;
    const s16x8 a = *(const s16x8*)(ob + (size_t)t * DIM + d);
    const s16x8 b = *(const s16x8*)(ob + (size_t)ms[t] * DIM + d);
    const s16x8 c = *(const s16x8*)(ob + (size_t)r0s[t] * DIM + d);
    const s16x8 e = *(const s16x8*)(ob + (size_t)r1s[t] * DIM + d);
    const float p0 = topkp[t * 2], p1 = topkp[t * 2 + 1];
    float o[8];
#pragma unroll
    for (int j = 0; j < 8; j++)
        o[j] = bf2f(a[j]) + bf2f(b[j]) + p0 * bf2f(c[j]) + p1 * bf2f(e[j]);
    float* dst = out + (size_t)t * DIM + d;
    *(float4*)dst = make_float4(o[0], o[1], o[2], o[3]);
    *(float4*)(dst + 4) = make_float4(o[4], o[5], o[6], o[7]);
}

extern "C" void kernel_launch(void* const* d_in, const int* in_sizes, int n_in,
                              void* d_out, int out_size, void* d_ws, size_t ws_size,
                              hipStream_t stream) {
    (void)in_sizes; (void)n_in; (void)out_size;
    if (ws_size < WS_NEED) return;

    const float* hidden   = (const float*)d_in[0];
    const int*   mode_ids = (const int*)d_in[1];
    const float* router_w = (const float*)d_in[2];
    const float* router_b = (const float*)d_in[3];
    TPtr tp;
    tp.s_w1 = (const float*)d_in[4];
    const float* s_b1 = (const float*)d_in[5];
    tp.s_w2 = (const float*)d_in[6];
    const float* s_b2 = (const float*)d_in[7];
    tp.m_w1 = (const float*)d_in[8];
    const float* m_b1 = (const float*)d_in[9];
    tp.m_w2 = (const float*)d_in[10];
    const float* m_b2 = (const float*)d_in[11];
    tp.r_w1 = (const float*)d_in[12];
    const float* r_b1 = (const float*)d_in[13];
    tp.r_w2 = (const float*)d_in[14];
    const float* r_b2 = (const float*)d_in[15];

    char* ws = (char*)d_ws;
    bf16t* WT1   = (bf16t*)(ws + OFF_WT1);
    bf16t* WT2   = (bf16t*)(ws + OFF_WT2);
    bf16t* Hbuf  = (bf16t*)(ws + OFF_HBUF);
    bf16t* Xbf   = (bf16t*)(ws + OFF_XBF);
    bf16t* Obuf  = (bf16t*)(ws + OFF_OBUF);
    float* B1c   = (float*)(ws + OFF_B1);
    float* B2c   = (float*)(ws + OFF_B2);
    float* topkp = (float*)(ws + OFF_TP);
    int*   topki = (int*)(ws + OFF_TI);
    int*   ms    = (int*)(ws + OFF_MS);
    int*   r0s   = (int*)(ws + OFF_R0S);
    int*   r1s   = (int*)(ws + OFF_R1S);
    int*   list  = (int*)(ws + OFF_LIST);
    int*   cnts  = (int*)(ws + OFF_CNT);
    int*   curs  = (int*)(ws + OFF_CUR);
    int*   tcnt  = (int*)(ws + OFF_TC);
    int4*  tdesc = (int4*)(ws + OFF_TD);

    float* out        = (float*)d_out;
    float* aux_logits = out + (size_t)NTOK * DIM;
    float* aux_idx    = aux_logits + (size_t)NTOK * NEXP;
    float* aux_probs  = aux_idx + (size_t)NTOK * 2;

    // zero list (incl. pad) + cnts + cursors
    hipMemsetAsync(ws + OFF_LIST, 0, OFF_TC - OFF_LIST, stream);

    transpose_convert_k<<<dim3(32, 32, 26), 256, 0, stream>>>(tp, WT1, WT2);
    xconv_k<<<(NTOK * DIM) / (256 * 8), 256, 0, stream>>>(hidden, Xbf);
    biascat_k<<<(NGRP * HID + 255) / 256, 256, 0, stream>>>(s_b1, m_b1, r_b1, s_b2, m_b2, r_b2, B1c, B2c);
    router_k<<<NTOK, 64, 0, stream>>>(hidden, mode_ids, router_w, router_b,
                                      aux_logits, aux_idx, aux_probs, topkp, topki, cnts);
    scan_k<<<1, 64, 0, stream>>>(cnts, curs, tdesc, tcnt);
    fill_k<<<(NTOK + 255) / 256, 256, 0, stream>>>(mode_ids, topki, curs, list, ms, r0s, r1s);
    ffn_gemm_k<1><<<(HID / 128) * MAXT, 256, 0, stream>>>(Xbf, Hbuf, WT1, B1c, Hbuf, list, tdesc, tcnt);
    ffn_gemm_k<2><<<(DIM / 128) * MAXT, 256, 0, stream>>>(Xbf, Hbuf, WT2, B2c, Obuf, list, tdesc, tcnt);
    reduce_k<<<NTOK, 128, 0, stream>>>(Obuf, ms, r0s, r1s, topkp, out);
}